// Round 12
// baseline (215.830 us; speedup 1.0000x reference)
//
#include <hip/hip_runtime.h>
#include <stdint.h>

typedef uint32_t u32;
typedef uint16_t u16;
typedef uint64_t u64;
typedef __attribute__((ext_vector_type(4))) float f32x4;
typedef __attribute__((ext_vector_type(4))) u32 u32x4;
typedef __attribute__((ext_vector_type(8))) short bf16x8;
typedef __attribute__((ext_vector_type(2))) _Float16 f16x2;

#define NI   10000
#define NPAD 10240
#define L2E  1.4426950408889634f

#define DEV static __device__ __forceinline__

DEV float asf(u32 u){ union{u32 i; float f;} v; v.i=u; return v.f; }
DEV u32   asu(float f){ union{u32 i; float f;} v; v.f=f; return v.i; }
DEV float bf2f(u16 u){ return asf(((u32)u)<<16); }
DEV u16   f2bf(float f){ u32 i = asu(f); return (u16)((i + 0x7fffu + ((i>>16)&1u))>>16); }
DEV f32x4 fzero(){ f32x4 z; z[0]=0.f; z[1]=0.f; z[2]=0.f; z[3]=0.f; return z; }

DEV void gl2lds16(const void* g, void* l){
  __builtin_amdgcn_global_load_lds((const __attribute__((address_space(1))) u32*)g,
                                   (__attribute__((address_space(3))) u32*)l, 16, 0, 0);
}

// ---------------------------------------------------------------- prep
__global__ void k_prep(const int* __restrict__ seq, const float* __restrict__ emb,
                       const float* __restrict__ wih, const float* __restrict__ bih,
                       const float* __restrict__ bhh, const float* __restrict__ W1,
                       const float* __restrict__ b1, const float* __restrict__ W2,
                       const float* __restrict__ alphas,
                       u16* __restrict__ EMB16, u16* __restrict__ Wih16,
                       u16* __restrict__ W1s16, u16* __restrict__ W1i16,
                       float* __restrict__ bias512, float* __restrict__ b1k,
                       float* __restrict__ w2hf, float* __restrict__ qv)
{
  const int tid = blockIdx.x*blockDim.x + threadIdx.x;
  const int nth = gridDim.x*blockDim.x;
  for (int e = tid; e < 10001*16; e += nth){
    const float* s = emb + (size_t)e*8;
    float4 x0 = *(const float4*)s, x1 = *(const float4*)(s+4);
    bf16x8 o;
    o[0]=(short)f2bf(x0.x); o[1]=(short)f2bf(x0.y); o[2]=(short)f2bf(x0.z); o[3]=(short)f2bf(x0.w);
    o[4]=(short)f2bf(x1.x); o[5]=(short)f2bf(x1.y); o[6]=(short)f2bf(x1.z); o[7]=(short)f2bf(x1.w);
    *(bf16x8*)&EMB16[(size_t)e*8] = o;
  }
  for (int e = tid; e < 512*16; e += nth){
    int col = (e*8)>>7;
    float sc = ((col>>7)==2) ? 2.0f*L2E : L2E;
    const float* s = wih + (size_t)e*8;
    float4 x0 = *(const float4*)s, x1 = *(const float4*)(s+4);
    bf16x8 o;
    o[0]=(short)f2bf(x0.x*sc); o[1]=(short)f2bf(x0.y*sc); o[2]=(short)f2bf(x0.z*sc); o[3]=(short)f2bf(x0.w*sc);
    o[4]=(short)f2bf(x1.x*sc); o[5]=(short)f2bf(x1.y*sc); o[6]=(short)f2bf(x1.z*sc); o[7]=(short)f2bf(x1.w*sc);
    *(bf16x8*)&Wih16[(size_t)e*8] = o;
  }
  for (int e = tid; e < 256*128; e += nth){ int k = e>>7, d = e&127; int l = k>>6, h = k&63;
      W1s16[e] = f2bf(W1[l*16384 + d*64 + h]); }
  for (int e = tid; e < 256*128; e += nth){ int k = e>>7, d = e&127; int l = k>>6, h = k&63;
      W1i16[e] = f2bf(W1[l*16384 + (128+d)*64 + h]); }
  for (int e = tid; e < 512; e += nth){
      float sc = ((e>>7)==2) ? 2.0f*L2E : L2E;
      bias512[e] = (bih[e] + bhh[e])*sc; }
  for (int e = tid; e < 256; e += nth){ int l = e>>6, h = e&63;
      b1k[e] = b1[l*64 + h]; }
  for (int e = tid; e < 256; e += nth)
      w2hf[e] = 0.5f*alphas[e>>6]*W2[(e>>6)*64 + (e&63)];
  // qv[d] = sum_k w2h[k] * W1s[k][d]   (for cB = H . qv)
  for (int d = tid; d < 128; d += nth){
    float s = 0.f;
    for (int k=0;k<256;++k){
      float wv = 0.5f*alphas[k>>6]*W2[(k>>6)*64 + (k&63)];
      s = fmaf(wv, W1[(k>>6)*16384 + d*64 + (k&63)], s);
    }
    qv[d] = s;
  }
}

// ---------------------------------------------------------------- K=128 MFMA GEMM body, 512 threads (8 waves)
// OUT_MODE: 0 f32 flat [M][ldc]; 4 XW LSTM-granule (A gathered via seq; rows = t*512+b);
//           7 IPFT f32 transposed [col][256] (rows contiguous per col)
// BIAS_MODE: 0 none, 1 per-col, 2 per-row
template<int OUT_MODE, int BIAS_MODE>
DEV void gemm_body(const u16* __restrict__ A, const u16* __restrict__ BT,
                   const float* __restrict__ bias, void* __restrict__ Cout,
                   int Nvalid, int ldc, int bx, int by, char* smem,
                   const int* __restrict__ seq)
{
  u16* sA = (u16*)smem;             // 128 rows x 256B
  u16* sB = (u16*)(smem + 32768);   // 64 rows x 256B
  const int tid = threadIdx.x, l = tid&63, w = tid>>6;   // 8 waves
  const int c16 = l&15, g4 = l>>4;
  const int m0 = bx*128, n0 = by*64;
  #pragma unroll
  for (int it=0; it<4; ++it){
    int row = it*32 + w*4 + g4;
    int sg  = c16 ^ (row&7);
    if constexpr (OUT_MODE==4){
      int b = (m0&511) + row, t = m0>>9;
      int idx = seq[b*50 + t];
      gl2lds16(A + (size_t)idx*128 + sg*8, (char*)sA + (it*32 + w*4)*256);
    } else {
      gl2lds16(A + (size_t)(m0+row)*128 + sg*8, (char*)sA + (it*32 + w*4)*256);
    }
  }
  #pragma unroll
  for (int it=0; it<2; ++it){
    int row = it*32 + w*4 + g4;
    int srow;
    if constexpr (OUT_MODE==4){
      int base1 = (by>>2)*256 + (by&3)*32;
      srow = base1 + (row&31) + (row>>5)*128;
    } else {
      srow = n0 + row; if (srow >= Nvalid) srow = Nvalid-1;
    }
    int sg  = c16 ^ (row&7);
    gl2lds16(BT + (size_t)srow*128 + sg*8, (char*)sB + (it*32 + w*4)*256);
  }
  __syncthreads();
  f32x4 acc[4];
  #pragma unroll
  for (int ct=0; ct<4; ++ct) acc[ct] = fzero();
  #pragma unroll
  for (int kt=0; kt<4; ++kt){
    bf16x8 a, b[4];
    int arow = w*16 + c16;
    a = *(const bf16x8*)((const char*)sA + arow*256 + (((kt*4+g4) ^ (arow&7))*16));
    #pragma unroll
    for (int ct=0; ct<4; ++ct){
      int brow = (OUT_MODE==4) ? ((ct>>1)*32 + (ct&1)*16 + c16) : (ct*16 + c16);
      b[ct] = *(const bf16x8*)((const char*)sB + brow*256 + (((kt*4+g4) ^ (brow&7))*16));
    }
    #pragma unroll
    for (int ct=0; ct<4; ++ct)
      acc[ct] = __builtin_amdgcn_mfma_f32_16x16x32_bf16(a, b[ct], acc[ct], 0, 0, 0);
  }
  const int rbase = m0 + w*16 + g4*4;
  if constexpr (OUT_MODE==4){
    int t    = rbase >> 9;
    int bloc = rbase & 511;
    int bb   = bloc >> 4;
    int g4l  = (bloc >> 2) & 3;
    int half = by >> 2;
    #pragma unroll
    for (int p=0; p<2; ++p){
      int colA = (by&3)*32 + p*16 + c16 + (by>>2)*256;
      int colB = colA + 128;
      u32 ws[4];
      #pragma unroll
      for (int i=0;i<4;++i){
        float va = acc[p][i], vb = acc[p+2][i];
        if constexpr (BIAS_MODE==1){ va += bias[colA]; vb += bias[colB]; }
        ws[i] = (u32)f2bf(va) | ((u32)f2bf(vb)<<16);
      }
      int tidl = ((by&3)*2 + p)*64 + g4l*16 + c16;
      char* dst = (char*)Cout + ((size_t)((t*32+bb)*1024 + half*512 + tidl))*16;
      *(f32x4*)dst = *(f32x4*)ws;
    }
  } else {
    #pragma unroll
    for (int ct=0; ct<4; ++ct){
      int col = n0 + ct*16 + c16;
      if (col < Nvalid){
        float v[4];
        #pragma unroll
        for (int i=0;i<4;++i){
          v[i] = acc[ct][i];
          if constexpr (BIAS_MODE==1) v[i] += bias[col];
          else if constexpr (BIAS_MODE==2) v[i] += bias[rbase+i];
        }
        if constexpr (OUT_MODE==0){
          float* C = (float*)Cout;
          #pragma unroll
          for (int i=0;i<4;++i) C[(size_t)(rbase+i)*ldc + col] = v[i];
        } else {  // OUT_MODE 7: f32 transposed [col][256], k-rows contiguous
          float* C = (float*)Cout;
          f32x4 vv; vv[0]=v[0]; vv[1]=v[1]; vv[2]=v[2]; vv[3]=v[3];
          *(f32x4*)&C[(size_t)col*256 + rbase] = vv;
        }
      }
    }
  }
}

template<int OUT_MODE, int BIAS_MODE>
__global__ __launch_bounds__(512) void k_gemm(const u16* __restrict__ A,
    const u16* __restrict__ BT, const float* __restrict__ bias,
    void* __restrict__ Cout, int Nvalid, int ldc, const int* __restrict__ seq)
{
  __shared__ __align__(16) char smem[49152];
  gemm_body<OUT_MODE,BIAS_MODE>(A, BT, bias, Cout, Nvalid, ldc, blockIdx.x, blockIdx.y, smem, seq);
}

// ---------------------------------------------------------------- LSTM body: 512 threads, 16 samples, 50 steps
DEV void lstm_body(const float* __restrict__ whh, const u16* __restrict__ XWL,
                   u16* __restrict__ H16, int bb, char* smem)
{
  const int tid = threadIdx.x, l = tid&63, w = tid>>6;   // 8 waves
  const int c16 = l&15, g4 = l>>4;
  const int u = w*16 + c16;
  bf16x8 bfr[4][4];
  #pragma unroll
  for (int j=0; j<4; ++j){
    int col = (j*8 + w)*16 + c16;
    float sc = (j==2) ? 2.0f*L2E : L2E;
    const float* src = whh + (size_t)col*128;
    #pragma unroll
    for (int kt=0; kt<4; ++kt){
      int k0 = kt*32 + g4*8;
      float4 x0 = *(const float4*)(src + k0);
      float4 x1 = *(const float4*)(src + k0 + 4);
      bf16x8 f;
      f[0]=(short)f2bf(x0.x*sc); f[1]=(short)f2bf(x0.y*sc); f[2]=(short)f2bf(x0.z*sc); f[3]=(short)f2bf(x0.w*sc);
      f[4]=(short)f2bf(x1.x*sc); f[5]=(short)f2bf(x1.y*sc); f[6]=(short)f2bf(x1.z*sc); f[7]=(short)f2bf(x1.w*sc);
      bfr[kt][j] = f;
    }
  }
  for (int e = tid; e < 4096; e += 512) ((u16*)smem)[e] = 0;
  int hoff[4];
  #pragma unroll
  for (int i=0;i<4;++i){ int s = g4*4 + i;
    hoff[i] = s*256 + (((u>>3) ^ (s&7))*16) + (u&7)*2; }
  const char* gb = (const char*)XWL;
  bf16x8 xv0[2], xv1[2];
  {
    size_t base = (size_t)bb*1024;
    xv0[0] = *(const bf16x8*)(gb + (base + tid)*16);
    xv1[0] = *(const bf16x8*)(gb + (base + 512 + tid)*16);
  }
  float cst[4] = {0.f,0.f,0.f,0.f};
  float hreg[4] = {0.f,0.f,0.f,0.f};
  __syncthreads();
  #pragma unroll 2
  for (int t=0; t<50; ++t){
    const int cur = t&1, nxt = cur^1;
    char* AhC = smem + cur*4096;
    char* AhN = smem + nxt*4096;
    if (t < 49){
      size_t base = (size_t)((t+1)*32+bb)*1024;
      xv0[nxt] = *(const bf16x8*)(gb + (base + tid)*16);
      xv1[nxt] = *(const bf16x8*)(gb + (base + 512 + tid)*16);
    }
    const u32* W0 = (const u32*)&xv0[cur];
    const u32* W1 = (const u32*)&xv1[cur];
    f32x4 acc[4];
    #pragma unroll
    for (int i=0;i<4;++i){
      acc[0][i] = asf(W0[i]<<16);
      acc[1][i] = asf(W0[i]&0xffff0000u);
      acc[2][i] = asf(W1[i]<<16);
      acc[3][i] = asf(W1[i]&0xffff0000u);
    }
    #pragma unroll
    for (int kt=0; kt<4; ++kt){
      bf16x8 a = *(const bf16x8*)(AhC + c16*256 + (((kt*4+g4) ^ (c16&7))*16));
      #pragma unroll
      for (int j=0; j<4; ++j)
        acc[j] = __builtin_amdgcn_mfma_f32_16x16x32_bf16(a, bfr[kt][j], acc[j], 0, 0, 0);
    }
    #pragma unroll
    for (int i=0;i<4;++i){
      float yi = acc[0][i], yf = acc[1][i], yg = acc[2][i], yo = acc[3][i];
      yg = fminf(fmaxf(yg, -40.f), 40.f);
      float Ei = __builtin_amdgcn_exp2f(-yi);
      float Ef = __builtin_amdgcn_exp2f(-yf);
      float G  = __builtin_amdgcn_exp2f(yg);
      float Eo = __builtin_amdgcn_exp2f(-yo);
      float ai = 1.f+Ei, af = 1.f+Ef, gp = G+1.f, gm = G-1.f;
      float num = fmaf(af, gm, cst[i]*ai*gp);
      float den = af*ai*gp;
      float cn  = num * __builtin_amdgcn_rcpf(den);
      cst[i] = cn;
      float yc = fminf(fmaxf(cn*(2.0f*L2E), -40.f), 40.f);
      float C2 = __builtin_amdgcn_exp2f(yc);
      float h  = (C2-1.f) * __builtin_amdgcn_rcpf((1.f+Eo)*(C2+1.f));
      hreg[i] = h;
      *(u16*)(AhN + hoff[i]) = f2bf(h);
    }
    asm volatile("s_waitcnt lgkmcnt(0)" ::: "memory");
    __builtin_amdgcn_s_barrier();
  }
  #pragma unroll
  for (int i=0;i<4;++i)
    H16[(size_t)(bb*16 + g4*4 + i)*128 + u] = f2bf(hreg[i]);
}

// ---------------------------------------------------------------- fused: blocks 0..31 LSTM, 32.. IPFT GEMM
__global__ __launch_bounds__(512) void k_lstm_ipf(const float* __restrict__ whh,
    const u16* __restrict__ XWL, u16* __restrict__ H16,
    const u16* __restrict__ W1i16, const u16* __restrict__ EMB16,
    const float* __restrict__ b1k, float* __restrict__ IPFT)
{
  __shared__ __align__(16) char smem[49152];
  if (blockIdx.x < 32){
    lstm_body(whh, XWL, H16, blockIdx.x, smem);
  } else {
    int g = blockIdx.x - 32;
    gemm_body<7,2>(W1i16, EMB16, b1k, IPFT, NI, 256, g&1, g>>1, smem, nullptr);
  }
}

// ---------------------------------------------------------------- post: SPf gemm (f32 flat) + cB + cN
__global__ __launch_bounds__(512) void k_post(const u16* __restrict__ H16,
    const u16* __restrict__ W1s16, float* __restrict__ SPf,
    const float* __restrict__ qv, float* __restrict__ cB,
    const float* __restrict__ IPFT, const float* __restrict__ b2,
    const float* __restrict__ alphas, const float* __restrict__ w2hf,
    float* __restrict__ cN)
{
  __shared__ __align__(16) char smem[49152];
  const int bid = blockIdx.x;
  if (bid < 16){                       // SP = H . W1s^T -> f32 [512][256]
    gemm_body<0,0>(H16, W1s16, nullptr, SPf, 256, 256, bid&3, bid>>2, smem, nullptr);
  } else if (bid == 16){               // cB[b] = sum_d H[b,d]*qv[d]
    int b = threadIdx.x;
    float s = 0.f;
    #pragma unroll
    for (int d8=0; d8<16; ++d8){
      bf16x8 hv = *(const bf16x8*)&H16[(size_t)b*128 + d8*8];
      #pragma unroll
      for (int j=0;j<8;++j) s = fmaf(bf2f((u16)hv[j]), qv[d8*8+j], s);
    }
    cB[b] = s;
  } else {                             // cN[n] = cb2 + sum_k ip[n,k]*w2h[k]
    int n = (bid-17)*512 + threadIdx.x;
    if (n >= NPAD) return;
    if (n >= NI){ cN[n] = 0.f; return; }
    float cb2 = 0.f;
    #pragma unroll
    for (int ll=0;ll<4;++ll) cb2 += alphas[ll]*b2[ll];
    float s = cb2;
    const float* r = IPFT + (size_t)n*256;
    #pragma unroll 4
    for (int k=0;k<256;k+=4){
      f32x4 v4 = *(const f32x4*)(r + k);
      s = fmaf(v4[0], w2hf[k],   s);
      s = fmaf(v4[1], w2hf[k+1], s);
      s = fmaf(v4[2], w2hf[k+2], s);
      s = fmaf(v4[3], w2hf[k+3], s);
    }
    cN[n] = s;
  }
}

// ---------------------------------------------------------------- scoring:
// out[b,n] = cB[b] + cN[n] + sum_k |sp+ip|*w2h
// full-rate f32: v_add_f32(s_sp, v_ip) + v_fma_f32(|t|, s_w2, acc) = 2 instr/elem.
// sp & w2 read with UNIFORM indices from global -> s_load via scalar cache.
// ip per-lane contiguous f32 rows -> dwordx4.
__global__ __launch_bounds__(256) void k_score(const float* __restrict__ SPf,
    const float* __restrict__ IPFT, const float* __restrict__ w2hf,
    const float* __restrict__ cB, const float* __restrict__ cN,
    float* __restrict__ out)
{
  const int tid = threadIdx.x;
  const int n  = blockIdx.x*256 + tid;
  const int b0 = blockIdx.y*16;
  const float cNv = cN[n];
  float acc[16];
  #pragma unroll
  for (int i=0;i<16;++i) acc[i] = cB[b0+i] + cNv;
  const float* iprow = IPFT + (size_t)n*256;
  #pragma unroll 1
  for (int kc=0; kc<64; ++kc){
    f32x4 ip4 = *(const f32x4*)(iprow + kc*4);
    const float w0 = w2hf[kc*4+0], w1 = w2hf[kc*4+1];
    const float w2 = w2hf[kc*4+2], w3 = w2hf[kc*4+3];
    #pragma unroll
    for (int i=0;i<16;++i){
      const float* sp = SPf + (size_t)(b0+i)*256 + kc*4;
      float a = acc[i];
      float t0 = sp[0] + ip4[0];
      float t1 = sp[1] + ip4[1];
      float t2 = sp[2] + ip4[2];
      float t3 = sp[3] + ip4[3];
      a = fmaf(fabsf(t0), w0, a);
      a = fmaf(fabsf(t1), w1, a);
      a = fmaf(fabsf(t2), w2, a);
      a = fmaf(fabsf(t3), w3, a);
      acc[i] = a;
    }
  }
  if (n < NI){
    #pragma unroll
    for (int i=0;i<16;++i) out[(size_t)(b0+i)*NI + n] = acc[i];
  }
}

// ---------------------------------------------------------------- loss
__global__ void k_loss(const float* __restrict__ scores, const int* __restrict__ pos,
                       const int* __restrict__ neg, float* __restrict__ outloss)
{
  __shared__ float red[256];
  int tid = threadIdx.x;
  float s = 0.f;
  for (int e = tid; e < 5120; e += 256){
    int b = e/10, j = e - b*10;
    float ps = scores[(size_t)b*NI + pos[b]];
    float ns = scores[(size_t)b*NI + neg[b*10 + j]];
    s += __expf(ns - ps);
  }
  red[tid] = s; __syncthreads();
  for (int st=128; st>0; st>>=1){ if (tid<st) red[tid]+=red[tid+st]; __syncthreads(); }
  if (tid==0) outloss[0] = red[0] * (1.0f/5120.0f);
}

// ---------------------------------------------------------------- launch
extern "C" void kernel_launch(void* const* d_in, const int* in_sizes, int n_in,
                              void* d_out, int out_size, void* d_ws, size_t ws_size,
                              hipStream_t stream)
{
  const int*   seq    = (const int*)d_in[1];
  const int*   pos    = (const int*)d_in[2];
  const int*   neg    = (const int*)d_in[3];
  const float* emb    = (const float*)d_in[7];
  const float* wih    = (const float*)d_in[8];
  const float* whh    = (const float*)d_in[9];
  const float* bih    = (const float*)d_in[10];
  const float* bhh    = (const float*)d_in[11];
  const float* W1     = (const float*)d_in[12];
  const float* b1     = (const float*)d_in[13];
  const float* W2     = (const float*)d_in[14];
  const float* b2     = (const float*)d_in[15];
  const float* alphas = (const float*)d_in[16];
  float* out = (float*)d_out;
  (void)in_sizes; (void)n_in; (void)out_size; (void)ws_size;

  char* p = (char*)d_ws;
  size_t off = 0;
  auto alloc = [&](size_t bytes)->char*{ char* r = p + off;
      off = (off + bytes + 255) & ~(size_t)255; return r; };
  u16*  EMB16   = (u16*)  alloc((size_t)10001*128*2);
  u16*  Wih16   = (u16*)  alloc((size_t)512*128*2);
  u16*  W1s16   = (u16*)  alloc((size_t)256*128*2);
  u16*  W1i16   = (u16*)  alloc((size_t)256*128*2);
  float* bias512= (float*)alloc(512*4);
  float* b1k    = (float*)alloc(256*4);
  float* w2hf   = (float*)alloc(256*4);
  float* qv     = (float*)alloc(128*4);
  u16*  XWL     = (u16*)  alloc((size_t)25600*512*2);   // LSTM granule layout
  u16*  H16     = (u16*)  alloc((size_t)512*128*2);
  float* SPf    = (float*)alloc((size_t)512*256*4);     // f32 flat [512][256]
  float* IPFT   = (float*)alloc((size_t)NPAD*256*4);    // f32 [n][256]
  float* cB     = (float*)alloc(512*4);
  float* cN     = (float*)alloc((size_t)NPAD*4);

  k_prep<<<512,256,0,stream>>>(seq, emb, wih, bih, bhh, W1, b1, W2, alphas,
                               EMB16, Wih16, W1s16, W1i16, bias512, b1k, w2hf, qv);
  k_gemm<4,1><<<dim3(200,8),512,0,stream>>>(EMB16, Wih16, bias512, XWL, 512, 512, seq);
  k_lstm_ipf<<<32 + 314,512,0,stream>>>(whh, XWL, H16, W1i16, EMB16, b1k, IPFT);
  k_post<<<37,512,0,stream>>>(H16, W1s16, SPf, qv, cB, IPFT, b2, alphas, w2hf, cN);
  k_score<<<dim3(40,32),256,0,stream>>>(SPf, IPFT, w2hf, cB, cN, out);
  k_loss<<<1,256,0,stream>>>(out, pos, neg, out + (size_t)512*NI);
}

// Round 13
// 166.456 us; speedup vs baseline: 1.2966x; 1.2966x over previous
//
#include <hip/hip_runtime.h>
#include <stdint.h>

typedef uint32_t u32;
typedef uint16_t u16;
typedef uint64_t u64;
typedef __attribute__((ext_vector_type(4))) float f32x4;
typedef __attribute__((ext_vector_type(4))) u32 u32x4;
typedef __attribute__((ext_vector_type(8))) short bf16x8;
typedef __attribute__((ext_vector_type(2))) _Float16 f16x2;

#define NI   10000
#define NPAD 10240
#define L2E  1.4426950408889634f

#define DEV static __device__ __forceinline__

DEV float asf(u32 u){ union{u32 i; float f;} v; v.i=u; return v.f; }
DEV u32   asu(float f){ union{u32 i; float f;} v; v.f=f; return v.i; }
DEV float bf2f(u16 u){ return asf(((u32)u)<<16); }
DEV u16   f2bf(float f){ u32 i = asu(f); return (u16)((i + 0x7fffu + ((i>>16)&1u))>>16); }
DEV u16   f2h(float f){ _Float16 h = (_Float16)f; return __builtin_bit_cast(u16, h); }
DEV f16x2 h2c(u32 x){ return __builtin_bit_cast(f16x2, x); }
DEV f32x4 fzero(){ f32x4 z; z[0]=0.f; z[1]=0.f; z[2]=0.f; z[3]=0.f; return z; }

DEV void gl2lds16(const void* g, void* l){
  __builtin_amdgcn_global_load_lds((const __attribute__((address_space(1))) u32*)g,
                                   (__attribute__((address_space(3))) u32*)l, 16, 0, 0);
}

// ---------------------------------------------------------------- prep
__global__ void k_prep(const int* __restrict__ seq, const float* __restrict__ emb,
                       const float* __restrict__ wih, const float* __restrict__ bih,
                       const float* __restrict__ bhh, const float* __restrict__ W1,
                       const float* __restrict__ b1, const float* __restrict__ W2,
                       const float* __restrict__ alphas,
                       u16* __restrict__ EMB16, u16* __restrict__ Wih16,
                       u16* __restrict__ W1s16, u16* __restrict__ W1i16,
                       float* __restrict__ bias512, float* __restrict__ b1k,
                       u32* __restrict__ w2p)
{
  const int tid = blockIdx.x*blockDim.x + threadIdx.x;
  const int nth = gridDim.x*blockDim.x;
  for (int e = tid; e < 10001*16; e += nth){
    const float* s = emb + (size_t)e*8;
    float4 x0 = *(const float4*)s, x1 = *(const float4*)(s+4);
    bf16x8 o;
    o[0]=(short)f2bf(x0.x); o[1]=(short)f2bf(x0.y); o[2]=(short)f2bf(x0.z); o[3]=(short)f2bf(x0.w);
    o[4]=(short)f2bf(x1.x); o[5]=(short)f2bf(x1.y); o[6]=(short)f2bf(x1.z); o[7]=(short)f2bf(x1.w);
    *(bf16x8*)&EMB16[(size_t)e*8] = o;
  }
  for (int e = tid; e < 512*16; e += nth){
    int col = (e*8)>>7;
    float sc = ((col>>7)==2) ? 2.0f*L2E : L2E;
    const float* s = wih + (size_t)e*8;
    float4 x0 = *(const float4*)s, x1 = *(const float4*)(s+4);
    bf16x8 o;
    o[0]=(short)f2bf(x0.x*sc); o[1]=(short)f2bf(x0.y*sc); o[2]=(short)f2bf(x0.z*sc); o[3]=(short)f2bf(x0.w*sc);
    o[4]=(short)f2bf(x1.x*sc); o[5]=(short)f2bf(x1.y*sc); o[6]=(short)f2bf(x1.z*sc); o[7]=(short)f2bf(x1.w*sc);
    *(bf16x8*)&Wih16[(size_t)e*8] = o;
  }
  for (int e = tid; e < 256*128; e += nth){ int k = e>>7, d = e&127; int l = k>>6, h = k&63;
      W1s16[e] = f2bf(W1[l*16384 + d*64 + h]); }
  for (int e = tid; e < 256*128; e += nth){ int k = e>>7, d = e&127; int l = k>>6, h = k&63;
      W1i16[e] = f2bf(W1[l*16384 + (128+d)*64 + h]); }
  for (int e = tid; e < 512; e += nth){
      float sc = ((e>>7)==2) ? 2.0f*L2E : L2E;
      bias512[e] = (bih[e] + bhh[e])*sc; }
  for (int e = tid; e < 256; e += nth){ int l = e>>6, h = e&63;
      b1k[e] = b1[l*64 + h]; }
  for (int e = tid; e < 128; e += nth){
      int k0 = 2*e, k1 = 2*e+1;
      float w0 = alphas[k0>>6]*W2[(k0>>6)*64 + (k0&63)];
      float w1 = alphas[k1>>6]*W2[(k1>>6)*64 + (k1&63)];
      w2p[e] = (u32)f2h(w0) | ((u32)f2h(w1)<<16); }
}

// ---------------------------------------------------------------- K=128 MFMA GEMM body, 512 threads (8 waves)
// OUT_MODE: 0 f32 flat; 1 f16 flat u16; 2 IPF flat packed f16 pairs [kp][ldc];
//           4 XW LSTM-granule (A gathered via seq; rows = t*512+b)
// BIAS_MODE: 0 none, 1 per-col, 2 per-row
template<int OUT_MODE, int BIAS_MODE>
DEV void gemm_body(const u16* __restrict__ A, const u16* __restrict__ BT,
                   const float* __restrict__ bias, void* __restrict__ Cout,
                   int Nvalid, int ldc, int bx, int by, char* smem,
                   const int* __restrict__ seq)
{
  u16* sA = (u16*)smem;             // 128 rows x 256B
  u16* sB = (u16*)(smem + 32768);   // 64 rows x 256B
  const int tid = threadIdx.x, l = tid&63, w = tid>>6;   // 8 waves
  const int c16 = l&15, g4 = l>>4;
  const int m0 = bx*128, n0 = by*64;
  #pragma unroll
  for (int it=0; it<4; ++it){
    int row = it*32 + w*4 + g4;
    int sg  = c16 ^ (row&7);
    if constexpr (OUT_MODE==4){
      int b = (m0&511) + row, t = m0>>9;
      int idx = seq[b*50 + t];
      gl2lds16(A + (size_t)idx*128 + sg*8, (char*)sA + (it*32 + w*4)*256);
    } else {
      gl2lds16(A + (size_t)(m0+row)*128 + sg*8, (char*)sA + (it*32 + w*4)*256);
    }
  }
  #pragma unroll
  for (int it=0; it<2; ++it){
    int row = it*32 + w*4 + g4;
    int srow;
    if constexpr (OUT_MODE==4){
      int base1 = (by>>2)*256 + (by&3)*32;
      srow = base1 + (row&31) + (row>>5)*128;
    } else {
      srow = n0 + row; if (srow >= Nvalid) srow = Nvalid-1;
    }
    int sg  = c16 ^ (row&7);
    gl2lds16(BT + (size_t)srow*128 + sg*8, (char*)sB + (it*32 + w*4)*256);
  }
  __syncthreads();
  f32x4 acc[4];
  #pragma unroll
  for (int ct=0; ct<4; ++ct) acc[ct] = fzero();
  #pragma unroll
  for (int kt=0; kt<4; ++kt){
    bf16x8 a, b[4];
    int arow = w*16 + c16;
    a = *(const bf16x8*)((const char*)sA + arow*256 + (((kt*4+g4) ^ (arow&7))*16));
    #pragma unroll
    for (int ct=0; ct<4; ++ct){
      int brow = (OUT_MODE==4) ? ((ct>>1)*32 + (ct&1)*16 + c16) : (ct*16 + c16);
      b[ct] = *(const bf16x8*)((const char*)sB + brow*256 + (((kt*4+g4) ^ (brow&7))*16));
    }
    #pragma unroll
    for (int ct=0; ct<4; ++ct)
      acc[ct] = __builtin_amdgcn_mfma_f32_16x16x32_bf16(a, b[ct], acc[ct], 0, 0, 0);
  }
  const int rbase = m0 + w*16 + g4*4;
  if constexpr (OUT_MODE==4){
    int t    = rbase >> 9;
    int bloc = rbase & 511;
    int bb   = bloc >> 4;
    int g4l  = (bloc >> 2) & 3;
    int half = by >> 2;
    #pragma unroll
    for (int p=0; p<2; ++p){
      int colA = (by&3)*32 + p*16 + c16 + (by>>2)*256;
      int colB = colA + 128;
      u32 ws[4];
      #pragma unroll
      for (int i=0;i<4;++i){
        float va = acc[p][i], vb = acc[p+2][i];
        if constexpr (BIAS_MODE==1){ va += bias[colA]; vb += bias[colB]; }
        ws[i] = (u32)f2bf(va) | ((u32)f2bf(vb)<<16);
      }
      int tidl = ((by&3)*2 + p)*64 + g4l*16 + c16;
      char* dst = (char*)Cout + ((size_t)((t*32+bb)*1024 + half*512 + tidl))*16;
      *(f32x4*)dst = *(f32x4*)ws;
    }
  } else {
    #pragma unroll
    for (int ct=0; ct<4; ++ct){
      int col = n0 + ct*16 + c16;
      if (col < Nvalid){
        float v[4];
        #pragma unroll
        for (int i=0;i<4;++i){
          v[i] = acc[ct][i];
          if constexpr (BIAS_MODE==1) v[i] += bias[col];
          else if constexpr (BIAS_MODE==2) v[i] += bias[rbase+i];
        }
        if constexpr (OUT_MODE==0){
          float* C = (float*)Cout;
          #pragma unroll
          for (int i=0;i<4;++i) C[(size_t)(rbase+i)*ldc + col] = v[i];
        } else if constexpr (OUT_MODE==1){
          u16* C = (u16*)Cout;
          #pragma unroll
          for (int i=0;i<4;++i) C[(size_t)(rbase+i)*ldc + col] = f2h(v[i]);
        } else {  // OUT_MODE 2: flat packed f16 pairs [kp][ldc]
          u32* C = (u32*)Cout;
          u32 w0 = (u32)f2h(v[0]) | ((u32)f2h(v[1])<<16);
          u32 w1 = (u32)f2h(v[2]) | ((u32)f2h(v[3])<<16);
          int kp0 = rbase>>1;
          C[(size_t)kp0*ldc + col]     = w0;
          C[(size_t)(kp0+1)*ldc + col] = w1;
        }
      }
    }
  }
}

template<int OUT_MODE, int BIAS_MODE>
__global__ __launch_bounds__(512) void k_gemm(const u16* __restrict__ A,
    const u16* __restrict__ BT, const float* __restrict__ bias,
    void* __restrict__ Cout, int Nvalid, int ldc, const int* __restrict__ seq)
{
  __shared__ __align__(16) char smem[49152];
  gemm_body<OUT_MODE,BIAS_MODE>(A, BT, bias, Cout, Nvalid, ldc, blockIdx.x, blockIdx.y, smem, seq);
}

// ---------------------------------------------------------------- LSTM body: 512 threads, 16 samples, 50 steps
// smem: Ah[2][4096] at 0 ; Xs[2][16384] at 8192  (round-6 form)
DEV void lstm_body(const float* __restrict__ whh, const u16* __restrict__ XWL,
                   u16* __restrict__ H16, int bb, char* smem)
{
  const int tid = threadIdx.x, l = tid&63, w = tid>>6;   // 8 waves
  const int c16 = l&15, g4 = l>>4;
  const int u = w*16 + c16;
  bf16x8 bfr[4][4];
  #pragma unroll
  for (int j=0; j<4; ++j){
    int col = (j*8 + w)*16 + c16;
    float sc = (j==2) ? 2.0f*L2E : L2E;
    const float* src = whh + (size_t)col*128;
    #pragma unroll
    for (int kt=0; kt<4; ++kt){
      int k0 = kt*32 + g4*8;
      float4 x0 = *(const float4*)(src + k0);
      float4 x1 = *(const float4*)(src + k0 + 4);
      bf16x8 f;
      f[0]=(short)f2bf(x0.x*sc); f[1]=(short)f2bf(x0.y*sc); f[2]=(short)f2bf(x0.z*sc); f[3]=(short)f2bf(x0.w*sc);
      f[4]=(short)f2bf(x1.x*sc); f[5]=(short)f2bf(x1.y*sc); f[6]=(short)f2bf(x1.z*sc); f[7]=(short)f2bf(x1.w*sc);
      bfr[kt][j] = f;
    }
  }
  for (int e = tid; e < 4096; e += 512) ((u16*)smem)[e] = 0;
  int hoff[4];
  #pragma unroll
  for (int i=0;i<4;++i){ int s = g4*4 + i;
    hoff[i] = s*256 + (((u>>3) ^ (s&7))*16) + (u&7)*2; }
  const char* gb = (const char*)XWL;
  {
    size_t base = (size_t)bb*1024;
    gl2lds16(gb + (base + tid)*16,        smem + 8192 + w*1024);
    gl2lds16(gb + (base + 512 + tid)*16,  smem + 8192 + 8192 + w*1024);
  }
  float cst[4] = {0.f,0.f,0.f,0.f};
  float hreg[4] = {0.f,0.f,0.f,0.f};
  __syncthreads();
  #pragma unroll 2
  for (int t=0; t<50; ++t){
    const int cur = t&1;
    char* AhC = smem + cur*4096;
    char* AhN = smem + (cur^1)*4096;
    char* XsC = smem + 8192 + cur*16384;
    char* XsN = smem + 8192 + (cur^1)*16384;
    if (t < 49){
      size_t base = (size_t)((t+1)*32+bb)*1024;
      gl2lds16(gb + (base + tid)*16,       XsN + w*1024);
      gl2lds16(gb + (base + 512 + tid)*16, XsN + 8192 + w*1024);
    }
    bf16x8 xv0 = *(const bf16x8*)(XsC + tid*16);
    bf16x8 xv1 = *(const bf16x8*)(XsC + 8192 + tid*16);
    const u32* W0 = (const u32*)&xv0;
    const u32* W1 = (const u32*)&xv1;
    f32x4 acc[4];
    #pragma unroll
    for (int i=0;i<4;++i){
      acc[0][i] = asf(W0[i]<<16);
      acc[1][i] = asf(W0[i]&0xffff0000u);
      acc[2][i] = asf(W1[i]<<16);
      acc[3][i] = asf(W1[i]&0xffff0000u);
    }
    #pragma unroll
    for (int kt=0; kt<4; ++kt){
      bf16x8 a = *(const bf16x8*)(AhC + c16*256 + (((kt*4+g4) ^ (c16&7))*16));
      #pragma unroll
      for (int j=0; j<4; ++j)
        acc[j] = __builtin_amdgcn_mfma_f32_16x16x32_bf16(a, bfr[kt][j], acc[j], 0, 0, 0);
    }
    #pragma unroll
    for (int i=0;i<4;++i){
      float yi = acc[0][i], yf = acc[1][i], yg = acc[2][i], yo = acc[3][i];
      yg = fminf(fmaxf(yg, -40.f), 40.f);
      float Ei = __builtin_amdgcn_exp2f(-yi);
      float Ef = __builtin_amdgcn_exp2f(-yf);
      float G  = __builtin_amdgcn_exp2f(yg);
      float Eo = __builtin_amdgcn_exp2f(-yo);
      float ai = 1.f+Ei, af = 1.f+Ef, gp = G+1.f, gm = G-1.f;
      float num = fmaf(af, gm, cst[i]*ai*gp);
      float den = af*ai*gp;
      float cn  = num * __builtin_amdgcn_rcpf(den);
      cst[i] = cn;
      float yc = fminf(fmaxf(cn*(2.0f*L2E), -40.f), 40.f);
      float C2 = __builtin_amdgcn_exp2f(yc);
      float h  = (C2-1.f) * __builtin_amdgcn_rcpf((1.f+Eo)*(C2+1.f));
      hreg[i] = h;
      *(u16*)(AhN + hoff[i]) = f2bf(h);
    }
    __syncthreads();
  }
  #pragma unroll
  for (int i=0;i<4;++i)
    H16[(size_t)(bb*16 + g4*4 + i)*128 + u] = f2bf(hreg[i]);
}

// ---------------------------------------------------------------- fused: blocks 0..31 LSTM, 32.. IPF GEMM
__global__ __launch_bounds__(512) void k_lstm_ipf(const float* __restrict__ whh,
    const u16* __restrict__ XWL, u16* __restrict__ H16,
    const u16* __restrict__ W1i16, const u16* __restrict__ EMB16,
    const float* __restrict__ b1k, u32* __restrict__ IPF)
{
  __shared__ __align__(16) char smem[49152];
  if (blockIdx.x < 32){
    lstm_body(whh, XWL, H16, blockIdx.x, smem);
  } else {
    int g = blockIdx.x - 32;
    gemm_body<2,2>(W1i16, EMB16, b1k, IPF, NI, NPAD, g&1, g>>1, smem, nullptr);
  }
}

// ---------------------------------------------------------------- post: SP = H . W1s^T -> f16 [512][256]
__global__ __launch_bounds__(512) void k_post(const u16* __restrict__ H16,
    const u16* __restrict__ W1s16, u16* __restrict__ SPH)
{
  __shared__ __align__(16) char smem[49152];
  gemm_body<1,0>(H16, W1s16, nullptr, SPH, 256, 256, blockIdx.x&3, blockIdx.x>>2, smem, nullptr);
}

// ---------------------------------------------------------------- scoring (pk-f16 plateau form)
DEV float fdot2(u32 ab, u32 w, float acc){
  asm("v_dot2_f32_f16 %0, %1, %2, %0" : "+v"(acc) : "v"(ab), "s"(w));
  return acc;
}
DEV u32 pkmax0(u32 t){
  u32 r; asm("v_pk_max_f16 %0, %1, 0" : "=v"(r) : "v"(t)); return r;
}

__global__ __launch_bounds__(256) void k_score(const u32* __restrict__ SPH,
    const u32* __restrict__ IPF, const u32* __restrict__ w2p,
    const float* __restrict__ alphas, const float* __restrict__ b2,
    float* __restrict__ out)
{
  __shared__ __align__(16) u32 sp_lds[16*128];
  const int tid = threadIdx.x;
  const int n  = blockIdx.x*256 + tid;
  const int b0 = blockIdx.y*16;
  {
    const u32* src = SPH + (size_t)b0*128 + tid*8;
    *(u32x4*)&sp_lds[tid*8]   = *(const u32x4*)src;
    *(u32x4*)&sp_lds[tid*8+4] = *(const u32x4*)(src+4);
  }
  float cb2 = 0.f;
  #pragma unroll
  for (int ll=0;ll<4;++ll) cb2 += alphas[ll]*b2[ll];
  __syncthreads();
  float acc[16];
  #pragma unroll
  for (int i=0;i<16;++i) acc[i] = cb2;
  #pragma unroll 1
  for (int c=0;c<4;++c){
    u32 iw[32];
    #pragma unroll
    for (int v=0; v<32; ++v) iw[v] = IPF[(size_t)(c*32+v)*NPAD + n];
    const u32* wp = w2p + c*32;
    #pragma unroll
    for (int i=0;i<16;++i){
      float a = acc[i];
      #pragma unroll
      for (int vq=0; vq<8; ++vq){
        u32x4 sp4 = *(const u32x4*)&sp_lds[i*128 + c*32 + vq*4];
        #pragma unroll
        for (int q=0;q<4;++q){
          f16x2 t = h2c(sp4[q]) + h2c(iw[vq*4+q]);
          u32 r = pkmax0(__builtin_bit_cast(u32, t));
          a = fdot2(r, wp[vq*4+q], a);
        }
      }
      acc[i] = a;
    }
  }
  if (n < NI){
    #pragma unroll
    for (int i=0;i<16;++i) out[(size_t)(b0+i)*NI + n] = acc[i];
  }
}

// ---------------------------------------------------------------- loss
__global__ void k_loss(const float* __restrict__ scores, const int* __restrict__ pos,
                       const int* __restrict__ neg, float* __restrict__ outloss)
{
  __shared__ float red[256];
  int tid = threadIdx.x;
  float s = 0.f;
  for (int e = tid; e < 5120; e += 256){
    int b = e/10, j = e - b*10;
    float ps = scores[(size_t)b*NI + pos[b]];
    float ns = scores[(size_t)b*NI + neg[b*10 + j]];
    s += __expf(ns - ps);
  }
  red[tid] = s; __syncthreads();
  for (int st=128; st>0; st>>=1){ if (tid<st) red[tid]+=red[tid+st]; __syncthreads(); }
  if (tid==0) outloss[0] = red[0] * (1.0f/5120.0f);
}

// ---------------------------------------------------------------- launch
extern "C" void kernel_launch(void* const* d_in, const int* in_sizes, int n_in,
                              void* d_out, int out_size, void* d_ws, size_t ws_size,
                              hipStream_t stream)
{
  const int*   seq    = (const int*)d_in[1];
  const int*   pos    = (const int*)d_in[2];
  const int*   neg    = (const int*)d_in[3];
  const float* emb    = (const float*)d_in[7];
  const float* wih    = (const float*)d_in[8];
  const float* whh    = (const float*)d_in[9];
  const float* bih    = (const float*)d_in[10];
  const float* bhh    = (const float*)d_in[11];
  const float* W1     = (const float*)d_in[12];
  const float* b1     = (const float*)d_in[13];
  const float* W2     = (const float*)d_in[14];
  const float* b2     = (const float*)d_in[15];
  const float* alphas = (const float*)d_in[16];
  float* out = (float*)d_out;
  (void)in_sizes; (void)n_in; (void)out_size; (void)ws_size;

  char* p = (char*)d_ws;
  size_t off = 0;
  auto alloc = [&](size_t bytes)->char*{ char* r = p + off;
      off = (off + bytes + 255) & ~(size_t)255; return r; };
  u16*  EMB16   = (u16*)  alloc((size_t)10001*128*2);
  u16*  Wih16   = (u16*)  alloc((size_t)512*128*2);
  u16*  W1s16   = (u16*)  alloc((size_t)256*128*2);
  u16*  W1i16   = (u16*)  alloc((size_t)256*128*2);
  float* bias512= (float*)alloc(512*4);
  float* b1k    = (float*)alloc(256*4);
  u32*  w2p     = (u32*)  alloc(128*4);
  u16*  XWL     = (u16*)  alloc((size_t)25600*512*2);   // LSTM granule layout
  u16*  H16     = (u16*)  alloc((size_t)512*128*2);
  u16*  SPH     = (u16*)  alloc((size_t)512*256*2);
  u32*  IPF     = (u32*)  alloc((size_t)128*NPAD*4);

  k_prep<<<512,256,0,stream>>>(seq, emb, wih, bih, bhh, W1, b1, W2, alphas,
                               EMB16, Wih16, W1s16, W1i16, bias512, b1k, w2p);
  k_gemm<4,1><<<dim3(200,8),512,0,stream>>>(EMB16, Wih16, bias512, XWL, 512, 512, seq);
  k_lstm_ipf<<<32 + 314,512,0,stream>>>(whh, XWL, H16, W1i16, EMB16, b1k, IPF);
  k_post<<<16,512,0,stream>>>(H16, W1s16, SPH);
  k_score<<<dim3(40,32),256,0,stream>>>((const u32*)SPH, IPF, w2p, alphas, b2, out);
  k_loss<<<1,256,0,stream>>>(out, pos, neg, out + (size_t)512*NI);
}

// Round 14
// 163.187 us; speedup vs baseline: 1.3226x; 1.0200x over previous
//
#include <hip/hip_runtime.h>
#include <stdint.h>

typedef uint32_t u32;
typedef uint16_t u16;
typedef uint64_t u64;
typedef __attribute__((ext_vector_type(4))) float f32x4;
typedef __attribute__((ext_vector_type(4))) u32 u32x4;
typedef __attribute__((ext_vector_type(8))) short bf16x8;
typedef __attribute__((ext_vector_type(2))) _Float16 f16x2;

#define NI   10000
#define NPAD 10240
#define L2E  1.4426950408889634f

#define DEV static __device__ __forceinline__

DEV float asf(u32 u){ union{u32 i; float f;} v; v.i=u; return v.f; }
DEV u32   asu(float f){ union{u32 i; float f;} v; v.f=f; return v.i; }
DEV float bf2f(u16 u){ return asf(((u32)u)<<16); }
DEV u16   f2bf(float f){ u32 i = asu(f); return (u16)((i + 0x7fffu + ((i>>16)&1u))>>16); }
DEV u16   f2h(float f){ _Float16 h = (_Float16)f; return __builtin_bit_cast(u16, h); }
DEV f16x2 h2c(u32 x){ return __builtin_bit_cast(f16x2, x); }
DEV f32x4 fzero(){ f32x4 z; z[0]=0.f; z[1]=0.f; z[2]=0.f; z[3]=0.f; return z; }

DEV void gl2lds16(const void* g, void* l){
  __builtin_amdgcn_global_load_lds((const __attribute__((address_space(1))) u32*)g,
                                   (__attribute__((address_space(3))) u32*)l, 16, 0, 0);
}

// ---------------------------------------------------------------- prep
__global__ void k_prep(const int* __restrict__ seq, const float* __restrict__ emb,
                       const float* __restrict__ wih, const float* __restrict__ bih,
                       const float* __restrict__ bhh, const float* __restrict__ W1,
                       const float* __restrict__ b1, const float* __restrict__ W2,
                       const float* __restrict__ alphas,
                       u16* __restrict__ EMB16, u16* __restrict__ Wih16,
                       u16* __restrict__ W1s16, u16* __restrict__ W1i16,
                       float* __restrict__ bias512, float* __restrict__ b1k,
                       u32* __restrict__ w2p)
{
  const int tid = blockIdx.x*blockDim.x + threadIdx.x;
  const int nth = gridDim.x*blockDim.x;
  for (int e = tid; e < 10001*16; e += nth){
    const float* s = emb + (size_t)e*8;
    float4 x0 = *(const float4*)s, x1 = *(const float4*)(s+4);
    bf16x8 o;
    o[0]=(short)f2bf(x0.x); o[1]=(short)f2bf(x0.y); o[2]=(short)f2bf(x0.z); o[3]=(short)f2bf(x0.w);
    o[4]=(short)f2bf(x1.x); o[5]=(short)f2bf(x1.y); o[6]=(short)f2bf(x1.z); o[7]=(short)f2bf(x1.w);
    *(bf16x8*)&EMB16[(size_t)e*8] = o;
  }
  for (int e = tid; e < 512*16; e += nth){
    int col = (e*8)>>7;
    float sc = ((col>>7)==2) ? 2.0f*L2E : L2E;
    const float* s = wih + (size_t)e*8;
    float4 x0 = *(const float4*)s, x1 = *(const float4*)(s+4);
    bf16x8 o;
    o[0]=(short)f2bf(x0.x*sc); o[1]=(short)f2bf(x0.y*sc); o[2]=(short)f2bf(x0.z*sc); o[3]=(short)f2bf(x0.w*sc);
    o[4]=(short)f2bf(x1.x*sc); o[5]=(short)f2bf(x1.y*sc); o[6]=(short)f2bf(x1.z*sc); o[7]=(short)f2bf(x1.w*sc);
    *(bf16x8*)&Wih16[(size_t)e*8] = o;
  }
  for (int e = tid; e < 256*128; e += nth){ int k = e>>7, d = e&127; int l = k>>6, h = k&63;
      W1s16[e] = f2bf(W1[l*16384 + d*64 + h]); }
  for (int e = tid; e < 256*128; e += nth){ int k = e>>7, d = e&127; int l = k>>6, h = k&63;
      W1i16[e] = f2bf(W1[l*16384 + (128+d)*64 + h]); }
  for (int e = tid; e < 512; e += nth){
      float sc = ((e>>7)==2) ? 2.0f*L2E : L2E;
      bias512[e] = (bih[e] + bhh[e])*sc; }
  for (int e = tid; e < 256; e += nth){ int l = e>>6, h = e&63;
      b1k[e] = b1[l*64 + h]; }
  for (int e = tid; e < 128; e += nth){
      int k0 = 2*e, k1 = 2*e+1;
      float w0 = alphas[k0>>6]*W2[(k0>>6)*64 + (k0&63)];
      float w1 = alphas[k1>>6]*W2[(k1>>6)*64 + (k1&63)];
      w2p[e] = (u32)f2h(w0) | ((u32)f2h(w1)<<16); }
}

// ---------------------------------------------------------------- K=128 MFMA GEMM body, 512 threads (8 waves)
// OUT_MODE: 0 f32 flat; 1 f16 flat u16; 2 IPF flat packed f16 pairs [kp][ldc];
//           4 XW LSTM-granule (A gathered via seq; rows = t*512+b)
// BIAS_MODE: 0 none, 1 per-col, 2 per-row
template<int OUT_MODE, int BIAS_MODE>
DEV void gemm_body(const u16* __restrict__ A, const u16* __restrict__ BT,
                   const float* __restrict__ bias, void* __restrict__ Cout,
                   int Nvalid, int ldc, int bx, int by, char* smem,
                   const int* __restrict__ seq)
{
  u16* sA = (u16*)smem;             // 128 rows x 256B
  u16* sB = (u16*)(smem + 32768);   // 64 rows x 256B
  const int tid = threadIdx.x, l = tid&63, w = tid>>6;   // 8 waves
  const int c16 = l&15, g4 = l>>4;
  const int m0 = bx*128, n0 = by*64;
  #pragma unroll
  for (int it=0; it<4; ++it){
    int row = it*32 + w*4 + g4;
    int sg  = c16 ^ (row&7);
    if constexpr (OUT_MODE==4){
      int b = (m0&511) + row, t = m0>>9;
      int idx = seq[b*50 + t];
      gl2lds16(A + (size_t)idx*128 + sg*8, (char*)sA + (it*32 + w*4)*256);
    } else {
      gl2lds16(A + (size_t)(m0+row)*128 + sg*8, (char*)sA + (it*32 + w*4)*256);
    }
  }
  #pragma unroll
  for (int it=0; it<2; ++it){
    int row = it*32 + w*4 + g4;
    int srow;
    if constexpr (OUT_MODE==4){
      int base1 = (by>>2)*256 + (by&3)*32;
      srow = base1 + (row&31) + (row>>5)*128;
    } else {
      srow = n0 + row; if (srow >= Nvalid) srow = Nvalid-1;
    }
    int sg  = c16 ^ (row&7);
    gl2lds16(BT + (size_t)srow*128 + sg*8, (char*)sB + (it*32 + w*4)*256);
  }
  __syncthreads();
  f32x4 acc[4];
  #pragma unroll
  for (int ct=0; ct<4; ++ct) acc[ct] = fzero();
  #pragma unroll
  for (int kt=0; kt<4; ++kt){
    bf16x8 a, b[4];
    int arow = w*16 + c16;
    a = *(const bf16x8*)((const char*)sA + arow*256 + (((kt*4+g4) ^ (arow&7))*16));
    #pragma unroll
    for (int ct=0; ct<4; ++ct){
      int brow = (OUT_MODE==4) ? ((ct>>1)*32 + (ct&1)*16 + c16) : (ct*16 + c16);
      b[ct] = *(const bf16x8*)((const char*)sB + brow*256 + (((kt*4+g4) ^ (brow&7))*16));
    }
    #pragma unroll
    for (int ct=0; ct<4; ++ct)
      acc[ct] = __builtin_amdgcn_mfma_f32_16x16x32_bf16(a, b[ct], acc[ct], 0, 0, 0);
  }
  const int rbase = m0 + w*16 + g4*4;
  if constexpr (OUT_MODE==4){
    int t    = rbase >> 9;
    int bloc = rbase & 511;
    int bb   = bloc >> 4;
    int g4l  = (bloc >> 2) & 3;
    int half = by >> 2;
    #pragma unroll
    for (int p=0; p<2; ++p){
      int colA = (by&3)*32 + p*16 + c16 + (by>>2)*256;
      int colB = colA + 128;
      u32 ws[4];
      #pragma unroll
      for (int i=0;i<4;++i){
        float va = acc[p][i], vb = acc[p+2][i];
        if constexpr (BIAS_MODE==1){ va += bias[colA]; vb += bias[colB]; }
        ws[i] = (u32)f2bf(va) | ((u32)f2bf(vb)<<16);
      }
      int tidl = ((by&3)*2 + p)*64 + g4l*16 + c16;
      char* dst = (char*)Cout + ((size_t)((t*32+bb)*1024 + half*512 + tidl))*16;
      *(f32x4*)dst = *(f32x4*)ws;
    }
  } else {
    #pragma unroll
    for (int ct=0; ct<4; ++ct){
      int col = n0 + ct*16 + c16;
      if (col < Nvalid){
        float v[4];
        #pragma unroll
        for (int i=0;i<4;++i){
          v[i] = acc[ct][i];
          if constexpr (BIAS_MODE==1) v[i] += bias[col];
          else if constexpr (BIAS_MODE==2) v[i] += bias[rbase+i];
        }
        if constexpr (OUT_MODE==0){
          float* C = (float*)Cout;
          #pragma unroll
          for (int i=0;i<4;++i) C[(size_t)(rbase+i)*ldc + col] = v[i];
        } else if constexpr (OUT_MODE==1){
          u16* C = (u16*)Cout;
          #pragma unroll
          for (int i=0;i<4;++i) C[(size_t)(rbase+i)*ldc + col] = f2h(v[i]);
        } else {  // OUT_MODE 2: flat packed f16 pairs [kp][ldc]
          u32* C = (u32*)Cout;
          u32 w0 = (u32)f2h(v[0]) | ((u32)f2h(v[1])<<16);
          u32 w1 = (u32)f2h(v[2]) | ((u32)f2h(v[3])<<16);
          int kp0 = rbase>>1;
          C[(size_t)kp0*ldc + col]     = w0;
          C[(size_t)(kp0+1)*ldc + col] = w1;
        }
      }
    }
  }
}

template<int OUT_MODE, int BIAS_MODE>
__global__ __launch_bounds__(512) void k_gemm(const u16* __restrict__ A,
    const u16* __restrict__ BT, const float* __restrict__ bias,
    void* __restrict__ Cout, int Nvalid, int ldc, const int* __restrict__ seq)
{
  __shared__ __align__(16) char smem[49152];
  gemm_body<OUT_MODE,BIAS_MODE>(A, BT, bias, Cout, Nvalid, ldc, blockIdx.x, blockIdx.y, smem, seq);
}

// ---------------------------------------------------------------- LSTM body: 512 threads, 16 samples, 50 steps
// smem: Ah[2][4096] at 0 ; Xs[2][16384] at 8192  (round-6 form)
DEV void lstm_body(const float* __restrict__ whh, const u16* __restrict__ XWL,
                   u16* __restrict__ H16, int bb, char* smem)
{
  const int tid = threadIdx.x, l = tid&63, w = tid>>6;   // 8 waves
  const int c16 = l&15, g4 = l>>4;
  const int u = w*16 + c16;
  bf16x8 bfr[4][4];
  #pragma unroll
  for (int j=0; j<4; ++j){
    int col = (j*8 + w)*16 + c16;
    float sc = (j==2) ? 2.0f*L2E : L2E;
    const float* src = whh + (size_t)col*128;
    #pragma unroll
    for (int kt=0; kt<4; ++kt){
      int k0 = kt*32 + g4*8;
      float4 x0 = *(const float4*)(src + k0);
      float4 x1 = *(const float4*)(src + k0 + 4);
      bf16x8 f;
      f[0]=(short)f2bf(x0.x*sc); f[1]=(short)f2bf(x0.y*sc); f[2]=(short)f2bf(x0.z*sc); f[3]=(short)f2bf(x0.w*sc);
      f[4]=(short)f2bf(x1.x*sc); f[5]=(short)f2bf(x1.y*sc); f[6]=(short)f2bf(x1.z*sc); f[7]=(short)f2bf(x1.w*sc);
      bfr[kt][j] = f;
    }
  }
  for (int e = tid; e < 4096; e += 512) ((u16*)smem)[e] = 0;
  int hoff[4];
  #pragma unroll
  for (int i=0;i<4;++i){ int s = g4*4 + i;
    hoff[i] = s*256 + (((u>>3) ^ (s&7))*16) + (u&7)*2; }
  const char* gb = (const char*)XWL;
  {
    size_t base = (size_t)bb*1024;
    gl2lds16(gb + (base + tid)*16,        smem + 8192 + w*1024);
    gl2lds16(gb + (base + 512 + tid)*16,  smem + 8192 + 8192 + w*1024);
  }
  float cst[4] = {0.f,0.f,0.f,0.f};
  float hreg[4] = {0.f,0.f,0.f,0.f};
  __syncthreads();
  #pragma unroll 2
  for (int t=0; t<50; ++t){
    const int cur = t&1;
    char* AhC = smem + cur*4096;
    char* AhN = smem + (cur^1)*4096;
    char* XsC = smem + 8192 + cur*16384;
    char* XsN = smem + 8192 + (cur^1)*16384;
    if (t < 49){
      size_t base = (size_t)((t+1)*32+bb)*1024;
      gl2lds16(gb + (base + tid)*16,       XsN + w*1024);
      gl2lds16(gb + (base + 512 + tid)*16, XsN + 8192 + w*1024);
    }
    bf16x8 xv0 = *(const bf16x8*)(XsC + tid*16);
    bf16x8 xv1 = *(const bf16x8*)(XsC + 8192 + tid*16);
    const u32* W0 = (const u32*)&xv0;
    const u32* W1 = (const u32*)&xv1;
    f32x4 acc[4];
    #pragma unroll
    for (int i=0;i<4;++i){
      acc[0][i] = asf(W0[i]<<16);
      acc[1][i] = asf(W0[i]&0xffff0000u);
      acc[2][i] = asf(W1[i]<<16);
      acc[3][i] = asf(W1[i]&0xffff0000u);
    }
    #pragma unroll
    for (int kt=0; kt<4; ++kt){
      bf16x8 a = *(const bf16x8*)(AhC + c16*256 + (((kt*4+g4) ^ (c16&7))*16));
      #pragma unroll
      for (int j=0; j<4; ++j)
        acc[j] = __builtin_amdgcn_mfma_f32_16x16x32_bf16(a, bfr[kt][j], acc[j], 0, 0, 0);
    }
    #pragma unroll
    for (int i=0;i<4;++i){
      float yi = acc[0][i], yf = acc[1][i], yg = acc[2][i], yo = acc[3][i];
      yg = fminf(fmaxf(yg, -40.f), 40.f);
      float Ei = __builtin_amdgcn_exp2f(-yi);
      float Ef = __builtin_amdgcn_exp2f(-yf);
      float G  = __builtin_amdgcn_exp2f(yg);
      float Eo = __builtin_amdgcn_exp2f(-yo);
      float ai = 1.f+Ei, af = 1.f+Ef, gp = G+1.f, gm = G-1.f;
      float num = fmaf(af, gm, cst[i]*ai*gp);
      float den = af*ai*gp;
      float cn  = num * __builtin_amdgcn_rcpf(den);
      cst[i] = cn;
      float yc = fminf(fmaxf(cn*(2.0f*L2E), -40.f), 40.f);
      float C2 = __builtin_amdgcn_exp2f(yc);
      float h  = (C2-1.f) * __builtin_amdgcn_rcpf((1.f+Eo)*(C2+1.f));
      hreg[i] = h;
      *(u16*)(AhN + hoff[i]) = f2bf(h);
    }
    __syncthreads();
  }
  #pragma unroll
  for (int i=0;i<4;++i)
    H16[(size_t)(bb*16 + g4*4 + i)*128 + u] = f2bf(hreg[i]);
}

// ---------------------------------------------------------------- fused: blocks 0..31 LSTM, 32.. IPF GEMM
__global__ __launch_bounds__(512) void k_lstm_ipf(const float* __restrict__ whh,
    const u16* __restrict__ XWL, u16* __restrict__ H16,
    const u16* __restrict__ W1i16, const u16* __restrict__ EMB16,
    const float* __restrict__ b1k, u32* __restrict__ IPF)
{
  __shared__ __align__(16) char smem[49152];
  if (blockIdx.x < 32){
    lstm_body(whh, XWL, H16, blockIdx.x, smem);
  } else {
    int g = blockIdx.x - 32;
    gemm_body<2,2>(W1i16, EMB16, b1k, IPF, NI, NPAD, g&1, g>>1, smem, nullptr);
  }
}

// ---------------------------------------------------------------- post: SP = H . W1s^T -> f16 [512][256]
__global__ __launch_bounds__(512) void k_post(const u16* __restrict__ H16,
    const u16* __restrict__ W1s16, u16* __restrict__ SPH)
{
  __shared__ __align__(16) char smem[49152];
  gemm_body<1,0>(H16, W1s16, nullptr, SPH, 256, 256, blockIdx.x&3, blockIdx.x>>2, smem, nullptr);
}

// ---------------------------------------------------------------- scoring (pk-f16, 8-row tiles, 2560 blocks)
DEV float fdot2(u32 ab, u32 w, float acc){
  asm("v_dot2_f32_f16 %0, %1, %2, %0" : "+v"(acc) : "v"(ab), "s"(w));
  return acc;
}
DEV u32 pkmax0(u32 t){
  u32 r; asm("v_pk_max_f16 %0, %1, 0" : "=v"(r) : "v"(t)); return r;
}

__global__ __launch_bounds__(256) void k_score(const u32* __restrict__ SPH,
    const u32* __restrict__ IPF, const u32* __restrict__ w2p,
    const float* __restrict__ alphas, const float* __restrict__ b2,
    float* __restrict__ out)
{
  __shared__ __align__(16) u32 sp_lds[8*128];
  const int tid = threadIdx.x;
  const int n  = blockIdx.x*256 + tid;
  const int b0 = blockIdx.y*8;
  {
    const u32* src = SPH + (size_t)b0*128 + tid*4;
    *(u32x4*)&sp_lds[tid*4] = *(const u32x4*)src;
  }
  float cb2 = 0.f;
  #pragma unroll
  for (int ll=0;ll<4;++ll) cb2 += alphas[ll]*b2[ll];
  __syncthreads();
  float acc[8];
  #pragma unroll
  for (int i=0;i<8;++i) acc[i] = cb2;
  #pragma unroll 1
  for (int c=0;c<4;++c){
    u32 iw[32];
    #pragma unroll
    for (int v=0; v<32; ++v) iw[v] = IPF[(size_t)(c*32+v)*NPAD + n];
    const u32* wp = w2p + c*32;
    #pragma unroll
    for (int i=0;i<8;++i){
      float a = acc[i];
      #pragma unroll
      for (int vq=0; vq<8; ++vq){
        u32x4 sp4 = *(const u32x4*)&sp_lds[i*128 + c*32 + vq*4];
        #pragma unroll
        for (int q=0;q<4;++q){
          f16x2 t = h2c(sp4[q]) + h2c(iw[vq*4+q]);
          u32 r = pkmax0(__builtin_bit_cast(u32, t));
          a = fdot2(r, wp[vq*4+q], a);
        }
      }
      acc[i] = a;
    }
  }
  if (n < NI){
    #pragma unroll
    for (int i=0;i<8;++i) out[(size_t)(b0+i)*NI + n] = acc[i];
  }
}

// ---------------------------------------------------------------- loss
__global__ void k_loss(const float* __restrict__ scores, const int* __restrict__ pos,
                       const int* __restrict__ neg, float* __restrict__ outloss)
{
  __shared__ float red[256];
  int tid = threadIdx.x;
  float s = 0.f;
  for (int e = tid; e < 5120; e += 256){
    int b = e/10, j = e - b*10;
    float ps = scores[(size_t)b*NI + pos[b]];
    float ns = scores[(size_t)b*NI + neg[b*10 + j]];
    s += __expf(ns - ps);
  }
  red[tid] = s; __syncthreads();
  for (int st=128; st>0; st>>=1){ if (tid<st) red[tid]+=red[tid+st]; __syncthreads(); }
  if (tid==0) outloss[0] = red[0] * (1.0f/5120.0f);
}

// ---------------------------------------------------------------- launch
extern "C" void kernel_launch(void* const* d_in, const int* in_sizes, int n_in,
                              void* d_out, int out_size, void* d_ws, size_t ws_size,
                              hipStream_t stream)
{
  const int*   seq    = (const int*)d_in[1];
  const int*   pos    = (const int*)d_in[2];
  const int*   neg    = (const int*)d_in[3];
  const float* emb    = (const float*)d_in[7];
  const float* wih    = (const float*)d_in[8];
  const float* whh    = (const float*)d_in[9];
  const float* bih    = (const float*)d_in[10];
  const float* bhh    = (const float*)d_in[11];
  const float* W1     = (const float*)d_in[12];
  const float* b1     = (const float*)d_in[13];
  const float* W2     = (const float*)d_in[14];
  const float* b2     = (const float*)d_in[15];
  const float* alphas = (const float*)d_in[16];
  float* out = (float*)d_out;
  (void)in_sizes; (void)n_in; (void)out_size; (void)ws_size;

  char* p = (char*)d_ws;
  size_t off = 0;
  auto alloc = [&](size_t bytes)->char*{ char* r = p + off;
      off = (off + bytes + 255) & ~(size_t)255; return r; };
  u16*  EMB16   = (u16*)  alloc((size_t)10001*128*2);
  u16*  Wih16   = (u16*)  alloc((size_t)512*128*2);
  u16*  W1s16   = (u16*)  alloc((size_t)256*128*2);
  u16*  W1i16   = (u16*)  alloc((size_t)256*128*2);
  float* bias512= (float*)alloc(512*4);
  float* b1k    = (float*)alloc(256*4);
  u32*  w2p     = (u32*)  alloc(128*4);
  u16*  XWL     = (u16*)  alloc((size_t)25600*512*2);   // LSTM granule layout
  u16*  H16     = (u16*)  alloc((size_t)512*128*2);
  u16*  SPH     = (u16*)  alloc((size_t)512*256*2);
  u32*  IPF     = (u32*)  alloc((size_t)128*NPAD*4);

  k_prep<<<512,256,0,stream>>>(seq, emb, wih, bih, bhh, W1, b1, W2, alphas,
                               EMB16, Wih16, W1s16, W1i16, bias512, b1k, w2p);
  k_gemm<4,1><<<dim3(200,8),512,0,stream>>>(EMB16, Wih16, bias512, XWL, 512, 512, seq);
  k_lstm_ipf<<<32 + 314,512,0,stream>>>(whh, XWL, H16, W1i16, EMB16, b1k, IPF);
  k_post<<<16,512,0,stream>>>(H16, W1s16, SPH);
  k_score<<<dim3(40,64),256,0,stream>>>((const u32*)SPH, IPF, w2p, alphas, b2, out);
  k_loss<<<1,256,0,stream>>>(out, pos, neg, out + (size_t)512*NI);
}